// Round 1
// 795.293 us; speedup vs baseline: 1.0659x; 1.0659x over previous
//
#include <hip/hip_runtime.h>
#include <hip/hip_bf16.h>

#define HOP 32
#define NB 8
#define NDIM 512
#define KDIM 32768
#define LDIM 64
#define TOUT ((KDIM - 1) * HOP + LDIM)   // 1048608
#define QTILE 64                          // q-groups (output frames) per block
#define CT_ROWS 72                        // staged c columns: [q0-8, q0+64)
#define NSPLIT 128                        // n-slice width (512 = 4 slices)
#define CT_STRIDE 136                     // padded row stride in shorts (272B, 16B-aligned)

typedef __bf16 bf16x8 __attribute__((ext_vector_type(8)));
typedef float floatx4 __attribute__((ext_vector_type(4)));

__device__ __forceinline__ unsigned short f2bf(float f) {
    unsigned int u = __float_as_uint(f);
    u += 0x7FFFu + ((u >> 16) & 1u);      // round-to-nearest-even
    return (unsigned short)(u >> 16);
}

// ---- pre-pass: V fp32 [64][512] -> bf16 bits in d_ws ----
__global__ void convert_v_kernel(const float* __restrict__ vf,
                                 unsigned short* __restrict__ vb) {
    int i = (blockIdx.x * 256 + threadIdx.x) * 4;   // 32 blocks x 256 thr x 4
    float4 v = *reinterpret_cast<const float4*>(vf + i);
    ushort4 o;
    o.x = f2bf(v.x); o.y = f2bf(v.y); o.z = f2bf(v.z); o.w = f2bf(v.w);
    *reinterpret_cast<ushort4*>(vb + i) = o;
}

// N-split double-buffered decoder:
//   out[32 x 64] = W[32 x 1024] * z[1024 x 64], contraction chunked into
//   4 slices of n=128; slice p+1 staged into LDS buffer ^1 while slice p
//   feeds the MFMAs. LDS = 2 x 72 x 136 x 2B = 38.25 KiB -> 4 blocks/CU.
__global__ __launch_bounds__(256, 4) void decoder_kernel(
        const float* __restrict__ cg,            // c fp32 [B][N][K]
        const unsigned short* __restrict__ vb,   // V bf16 bits [L][N] (from ws)
        float* __restrict__ outg)                // [B][TOUT] fp32
{
    __shared__ __align__(16) unsigned short ct[2][CT_ROWS * CT_STRIDE];

    const int tid  = threadIdx.x;
    const int tile = blockIdx.x;
    const int b    = blockIdx.y;
    const int q0   = tile * QTILE;
    const int lane = tid & 63;

    const long cbase = (long)b * NDIM * KDIM;
    const bool fastA = (q0 + QTILE <= KDIM);
    const bool fastB = (q0 >= 8);

    const int w   = tid >> 6;             // wave id = column tile (0..3)
    const int l15 = lane & 15;
    const int g   = lane >> 4;
    const int jlo = w * 16 + l15;         // this lane's output column (local q)

    floatx4 acc0 = {0.f, 0.f, 0.f, 0.f};
    floatx4 acc1 = {0.f, 0.f, 0.f, 0.f};

    // stage n-slice [n0, n0+128) into buffer s (transpose fp32->bf16)
    auto stage = [&](int n0, int s) {
        // main 64 cols c[b][n][q0 .. q0+64) -> rows 8..71
        #pragma unroll
        for (int it = 0; it < 8; ++it) {
            int id = it * 256 + tid;      // 0..2047 = 128 rows * 16 chunks
            int n  = id >> 4;
            int cc = id & 15;             // chunk of 4 fp32 cols
            int colbase = q0 + cc * 4;
            float4 v;
            if (fastA) {
                v = *reinterpret_cast<const float4*>(cg + cbase + (long)(n0 + n) * KDIM + colbase);
            } else {
                float* ve = reinterpret_cast<float*>(&v);
                #pragma unroll
                for (int e = 0; e < 4; ++e) {
                    int col = colbase + e;
                    ve[e] = (col < KDIM) ? cg[cbase + (long)(n0 + n) * KDIM + col] : 0.f;
                }
            }
            unsigned short sr[4];
            sr[0] = f2bf(v.x); sr[1] = f2bf(v.y); sr[2] = f2bf(v.z); sr[3] = f2bf(v.w);
            #pragma unroll
            for (int i = 0; i < 4; ++i) {
                int e = (lane + i) & 3;   // rotate to spread LDS banks
                ct[s][(8 + cc * 4 + e) * CT_STRIDE + n] = sr[e];
            }
        }
        // halo 8 cols c[b][n][q0-8 .. q0) -> rows 0..7 (1 iter: 128 rows * 2 chunks)
        {
            int n  = tid >> 1;
            int cc = tid & 1;
            int colbase = q0 - 8 + cc * 4;
            float4 v;
            if (fastB) {
                v = *reinterpret_cast<const float4*>(cg + cbase + (long)(n0 + n) * KDIM + colbase);
            } else {
                float* ve = reinterpret_cast<float*>(&v);
                #pragma unroll
                for (int e = 0; e < 4; ++e) {
                    int col = colbase + e;
                    ve[e] = (col >= 0) ? cg[cbase + (long)(n0 + n) * KDIM + col] : 0.f;
                }
            }
            unsigned short sr[4];
            sr[0] = f2bf(v.x); sr[1] = f2bf(v.y); sr[2] = f2bf(v.z); sr[3] = f2bf(v.w);
            #pragma unroll
            for (int i = 0; i < 4; ++i) {
                int e = (lane + i) & 3;
                ct[s][(cc * 4 + e) * CT_STRIDE + n] = sr[e];
            }
        }
    };

    // consume n-slice [n0, n0+128) from buffer s
    auto mma = [&](int n0, int s) {
        #pragma unroll
        for (int ks = 0; ks < 8; ++ks) {
            const int hi   = (ks >= 4);
            const int ncol = (ks & 3) * 32 + g * 8;
            // B fragment: lane holds z[k_local = g*8+j][q = q0 + jlo]
            const unsigned short* bp = &ct[s][(jlo + (hi ? 7 : 8)) * CT_STRIDE + ncol];
            bf16x8 bfrag = *reinterpret_cast<const bf16x8*>(bp);
            // A fragments: W[m][k_local] from bf16 ws (L1/L2-hot)
            const int vrow0 = l15 + (hi ? 32 : 0);
            bf16x8 a0 = *reinterpret_cast<const bf16x8*>(vb + vrow0 * NDIM + n0 + ncol);
            bf16x8 a1 = *reinterpret_cast<const bf16x8*>(vb + (vrow0 + 16) * NDIM + n0 + ncol);
            acc0 = __builtin_amdgcn_mfma_f32_16x16x32_bf16(a0, bfrag, acc0, 0, 0, 0);
            acc1 = __builtin_amdgcn_mfma_f32_16x16x32_bf16(a1, bfrag, acc1, 0, 0, 0);
        }
    };

    stage(0, 0);
    __syncthreads();
    #pragma unroll
    for (int p = 0; p < 4; ++p) {
        if (p < 3) stage((p + 1) * NSPLIT, (p + 1) & 1);   // prefetch next slice
        mma(p * NSPLIT, p & 1);                            // consume current slice
        __syncthreads();
    }

    // ---- epilogue: D col(lane&15)=q-local, row((lane>>4)*4+reg)=r ----
    const int q = q0 + w * 16 + l15;
    if (q <= KDIM) {
        long tb = (long)b * TOUT + (long)q * HOP + g * 4;
        *reinterpret_cast<floatx4*>(outg + tb)      = acc0;   // r = g*4 .. g*4+3
        *reinterpret_cast<floatx4*>(outg + tb + 16) = acc1;   // r = 16+g*4 ..
    }
}

extern "C" void kernel_launch(void* const* d_in, const int* in_sizes, int n_in,
                              void* d_out, int out_size, void* d_ws, size_t ws_size,
                              hipStream_t stream) {
    const float* c  = (const float*)d_in[0];
    const float* V  = (const float*)d_in[1];
    float* out      = (float*)d_out;
    unsigned short* vb = (unsigned short*)d_ws;   // 64*512 bf16 = 64 KB

    convert_v_kernel<<<dim3(32), dim3(256), 0, stream>>>(V, vb);
    dim3 grid(KDIM / QTILE + 1, NB);   // (513, 8)
    decoder_kernel<<<grid, dim3(256, 1, 1), 0, stream>>>(c, vb, out);
}

// Round 2
// 762.161 us; speedup vs baseline: 1.1122x; 1.0435x over previous
//
#include <hip/hip_runtime.h>
#include <hip/hip_bf16.h>

#define HOP 32
#define NB 8
#define NDIM 512
#define KDIM 32768
#define LDIM 64
#define TOUT ((KDIM - 1) * HOP + LDIM)   // 1048608
#define QTILE 64                          // q-groups (output frames) per block
#define HALO 4                            // staged halo cols (need only q0-1)
#define CT_ROWS 68                        // 4 halo + 64 main c columns
#define NSPLIT 128                        // n-slice width (512 = 4 slices)
#define CT_STRIDE 136                     // shorts; 272 B row stride, 16B-aligned

typedef __bf16 bf16x8 __attribute__((ext_vector_type(8)));
typedef float floatx4 __attribute__((ext_vector_type(4)));

__device__ __forceinline__ unsigned short f2bf(float f) {
    unsigned int u = __float_as_uint(f);
    u += 0x7FFFu + ((u >> 16) & 1u);      // round-to-nearest-even
    return (unsigned short)(u >> 16);
}

// ---- pre-pass: V fp32 [64][512] -> bf16 bits in d_ws ----
__global__ void convert_v_kernel(const float* __restrict__ vf,
                                 unsigned short* __restrict__ vb) {
    int i = (blockIdx.x * 256 + threadIdx.x) * 4;   // 32 blocks x 256 thr x 4
    float4 v = *reinterpret_cast<const float4*>(vf + i);
    ushort4 o;
    o.x = f2bf(v.x); o.y = f2bf(v.y); o.z = f2bf(v.z); o.w = f2bf(v.w);
    *reinterpret_cast<ushort4*>(vb + i) = o;
}

// N-split double-buffered decoder, quad-packed LDS staging:
//   out[32 x 64] = W[32 x 1024] * z[1024 x 64], contraction in 4 n-slices.
//   Stage writes are ushort4 (4 n's per write) -> 8 b64 + 4 b16 per thread
//   per slice instead of 36 b16. LDS = 2 x 68 x 136 x 2B = 36.1 KiB -> 4/CU.
__global__ __launch_bounds__(256, 4) void decoder_kernel(
        const float* __restrict__ cg,            // c fp32 [B][N][K]
        const unsigned short* __restrict__ vb,   // V bf16 bits [L][N] (from ws)
        float* __restrict__ outg)                // [B][TOUT] fp32
{
    __shared__ __align__(16) unsigned short ct[2][CT_ROWS * CT_STRIDE];

    const int tid  = threadIdx.x;
    const int b    = blockIdx.y;
    const int lane = tid & 63;

    // bijective XCD-chunked tile swizzle (nwg=513, 513%8!=0 -> m204 form):
    // consecutive tiles land on the same XCD so tile t's halo line is tile
    // t-1's last main line -> L2 hit instead of duplicate HBM fetch.
    const int nwg  = gridDim.x;               // 513
    const int qd   = nwg >> 3, r = nwg & 7;
    const int xcd  = blockIdx.x & 7, idx = blockIdx.x >> 3;
    const int tile = (xcd < r ? xcd * (qd + 1) : r * (qd + 1) + (xcd - r) * qd) + idx;
    const int q0   = tile * QTILE;

    const long cbase = (long)b * NDIM * KDIM;
    const bool fastA = (q0 + QTILE <= KDIM);
    const bool fastB = (q0 >= HALO);

    const int w   = tid >> 6;             // wave id = column tile (0..3)
    const int l15 = lane & 15;
    const int g   = lane >> 4;
    const int jlo = w * 16 + l15;         // this lane's output column (local q)

    floatx4 acc0 = {0.f, 0.f, 0.f, 0.f};
    floatx4 acc1 = {0.f, 0.f, 0.f, 0.f};

    // stage n-slice [n0, n0+128) into buffer sb (transpose fp32->bf16)
    auto stage = [&](int n0, int sb) {
        // main 64 cols: 512 quad-tasks = 32 n-quads x 16 col-chunks
        #pragma unroll
        for (int it = 0; it < 2; ++it) {
            int id = it * 256 + tid;
            int nq = id >> 4;             // n-quad (4 rows)
            int cc = id & 15;             // chunk of 4 fp32 cols
            int colbase = q0 + cc * 4;
            float4 v[4];
            if (fastA) {
                #pragma unroll
                for (int rr = 0; rr < 4; ++rr)
                    v[rr] = *reinterpret_cast<const float4*>(
                        cg + cbase + (long)(n0 + 4 * nq + rr) * KDIM + colbase);
            } else {
                #pragma unroll
                for (int rr = 0; rr < 4; ++rr) {
                    float* ve = reinterpret_cast<float*>(&v[rr]);
                    #pragma unroll
                    for (int e = 0; e < 4; ++e) {
                        int col = colbase + e;
                        ve[e] = (col < KDIM)
                              ? cg[cbase + (long)(n0 + 4 * nq + rr) * KDIM + col] : 0.f;
                    }
                }
            }
            unsigned short s4[4][4];
            #pragma unroll
            for (int rr = 0; rr < 4; ++rr) {
                s4[rr][0] = f2bf(v[rr].x); s4[rr][1] = f2bf(v[rr].y);
                s4[rr][2] = f2bf(v[rr].z); s4[rr][3] = f2bf(v[rr].w);
            }
            #pragma unroll
            for (int i = 0; i < 4; ++i) {
                int ee = (lane + i) & 3;  // rotate to spread LDS banks
                ushort4 w4;
                w4.x = s4[0][ee]; w4.y = s4[1][ee]; w4.z = s4[2][ee]; w4.w = s4[3][ee];
                *reinterpret_cast<ushort4*>(
                    &ct[sb][(HALO + cc * 4 + ee) * CT_STRIDE + 4 * nq]) = w4;
            }
        }
        // halo 4 cols c[b][n][q0-4 .. q0) -> rows 0..3 (threads 0..127, 1 row each)
        if (tid < 128) {
            int n = tid;
            int colbase = q0 - HALO;
            float4 v;
            if (fastB) {
                v = *reinterpret_cast<const float4*>(
                    cg + cbase + (long)(n0 + n) * KDIM + colbase);
            } else {
                float* ve = reinterpret_cast<float*>(&v);
                #pragma unroll
                for (int e = 0; e < 4; ++e) {
                    int col = colbase + e;
                    ve[e] = (col >= 0) ? cg[cbase + (long)(n0 + n) * KDIM + col] : 0.f;
                }
            }
            unsigned short sr[4];
            sr[0] = f2bf(v.x); sr[1] = f2bf(v.y); sr[2] = f2bf(v.z); sr[3] = f2bf(v.w);
            #pragma unroll
            for (int i = 0; i < 4; ++i) {
                int ee = (lane + i) & 3;
                ct[sb][ee * CT_STRIDE + n] = sr[ee];
            }
        }
    };

    // consume n-slice [n0, n0+128) from buffer sb
    auto mma = [&](int n0, int sb) {
        #pragma unroll
        for (int ks = 0; ks < 8; ++ks) {
            const int hi   = (ks >= 4);
            const int ncol = (ks & 3) * 32 + g * 8;
            // B fragment: lane holds z[k_local = g*8+j][q = q0 + jlo]
            const unsigned short* bp =
                &ct[sb][(jlo + (hi ? HALO - 1 : HALO)) * CT_STRIDE + ncol];
            bf16x8 bfrag = *reinterpret_cast<const bf16x8*>(bp);
            // A fragments: W[m][k_local] from bf16 ws (L1/L2-hot)
            const int vrow0 = l15 + (hi ? 32 : 0);
            bf16x8 a0 = *reinterpret_cast<const bf16x8*>(vb + vrow0 * NDIM + n0 + ncol);
            bf16x8 a1 = *reinterpret_cast<const bf16x8*>(vb + (vrow0 + 16) * NDIM + n0 + ncol);
            acc0 = __builtin_amdgcn_mfma_f32_16x16x32_bf16(a0, bfrag, acc0, 0, 0, 0);
            acc1 = __builtin_amdgcn_mfma_f32_16x16x32_bf16(a1, bfrag, acc1, 0, 0, 0);
        }
    };

    stage(0, 0);
    __syncthreads();
    #pragma unroll
    for (int p = 0; p < 4; ++p) {
        if (p < 3) stage((p + 1) * NSPLIT, (p + 1) & 1);   // prefetch next slice
        mma(p * NSPLIT, p & 1);                            // consume current slice
        __syncthreads();
    }

    // ---- epilogue: D col(lane&15)=q-local, row((lane>>4)*4+reg)=r ----
    const int q = q0 + w * 16 + l15;
    if (q <= KDIM) {
        long tb = (long)b * TOUT + (long)q * HOP + g * 4;
        *reinterpret_cast<floatx4*>(outg + tb)      = acc0;   // r = g*4 .. g*4+3
        *reinterpret_cast<floatx4*>(outg + tb + 16) = acc1;   // r = 16+g*4 ..
    }
}

extern "C" void kernel_launch(void* const* d_in, const int* in_sizes, int n_in,
                              void* d_out, int out_size, void* d_ws, size_t ws_size,
                              hipStream_t stream) {
    const float* c  = (const float*)d_in[0];
    const float* V  = (const float*)d_in[1];
    float* out      = (float*)d_out;
    unsigned short* vb = (unsigned short*)d_ws;   // 64*512 bf16 = 64 KB

    convert_v_kernel<<<dim3(32), dim3(256), 0, stream>>>(V, vb);
    dim3 grid(KDIM / QTILE + 1, NB);   // (513, 8)
    decoder_kernel<<<grid, dim3(256, 1, 1), 0, stream>>>(c, vb, out);
}